// Round 4
// baseline (5780.264 us; speedup 1.0000x reference)
//
#include <hip/hip_runtime.h>

#define B_ 64
#define S_ 512
#define H_ 512

typedef unsigned short u16;
typedef unsigned int   u32;

typedef __attribute__((ext_vector_type(8))) short    bf16x8;
typedef __attribute__((ext_vector_type(8))) _Float16 f16x8;
typedef __attribute__((ext_vector_type(4))) float    f32x4;
typedef __attribute__((ext_vector_type(2))) _Float16 h2_t;

#define PJ_GATE ((size_t)512 * 64 * 512)   // P stride per gate: [512 ts][64 b][512 j]

// ---------- helpers ----------
__device__ inline u16 f2bf(float f) {            // RNE fp32 -> bf16 bits
  u32 u = __builtin_bit_cast(u32, f);
  u32 r = (u + 0x7fffu + ((u >> 16) & 1u)) >> 16;
  return (u16)r;
}
__device__ inline u32 pkbf2(float a, float b) {
  return (u32)f2bf(a) | ((u32)f2bf(b) << 16);
}
__device__ inline u32 pk2h(float a, float b) {   // pack two f32 -> half2 bits
  _Float16 x = (_Float16)a, y = (_Float16)b;
  return (u32)__builtin_bit_cast(u16, x) | ((u32)__builtin_bit_cast(u16, y) << 16);
}
__device__ inline float sigmoidf_(float x) { return 1.f / (1.f + __expf(-x)); }
__device__ inline float tanhf_(float x) {
  float e = __expf(-2.f * fabsf(x));
  float t = (1.f - e) / (1.f + e);
  return copysignf(t, x);
}

// ---------- kernel 1: W recurrent half -> f16 MFMA A-fragments ----------
// WF[g][rt][kt][lane] (uint4) : 8 f16 = W_g[rt*16 + (lane&15)][512 + kt*32 + (lane>>4)*8 + 0..7]
__global__ void k_convert_w(const float* __restrict__ Wr, const float* __restrict__ Wz,
                            const float* __restrict__ Wh, uint4* __restrict__ WF) {
  int g = blockIdx.y;
  const float* Ws = (g == 0) ? Wr : ((g == 1) ? Wz : Wh);
  int i = blockIdx.x * 256 + threadIdx.x;   // 0..32767
  int lane = i & 63;
  int kt   = (i >> 6) & 15;
  int rt   = i >> 10;                       // 0..31
  int row  = rt * 16 + (lane & 15);
  int col  = 512 + kt * 32 + (lane >> 4) * 8;
  const float* src = Ws + (size_t)row * 1024 + col;
  float4 a = *(const float4*)src;
  float4 b = *(const float4*)(src + 4);
  uint4 o;
  o.x = pk2h(a.x, a.y); o.y = pk2h(a.z, a.w);
  o.z = pk2h(b.x, b.y); o.w = pk2h(b.z, b.w);
  WF[((size_t)(g * 32 + rt) * 16 + kt) * 64 + lane] = o;
}

// ---------- kernel 2: projection GEMM (f32 in, bf16 MFMA, f16 out) ----------
// P[g][s][b][j] = f16( sum_k x[b,s,k]*W_g[j,k] + bias_g[j] )
__global__ __launch_bounds__(256) void k_proj_gemm(
    const float* __restrict__ x,      // [B*S][512] f32 (rows m = b*512+s)
    const float* __restrict__ Wr, const float* __restrict__ Wz, const float* __restrict__ Wh,
    const float* __restrict__ br, const float* __restrict__ bz, const float* __restrict__ bh,
    u16* __restrict__ P)
{
  const int g  = blockIdx.z;
  const int bm = blockIdx.x * 64;
  const int bn = blockIdx.y * 64;
  const float* Ws = (g == 0) ? Wr : ((g == 1) ? Wz : Wh);
  __shared__ __align__(16) u16 As[64][32];
  __shared__ __align__(16) u16 Bs[64][32];
  const int tid  = threadIdx.x;
  const int lane = tid & 63;
  const int wm   = (tid >> 6) >> 1;
  const int wn   = (tid >> 6) & 1;
  const int srow = tid >> 2;
  const int scol = (tid & 3) * 8;

  f32x4 zero4 = {0.f, 0.f, 0.f, 0.f};
  f32x4 acc[2][2];
  acc[0][0] = zero4; acc[0][1] = zero4; acc[1][0] = zero4; acc[1][1] = zero4;

  for (int k0 = 0; k0 < 512; k0 += 32) {
    __syncthreads();
    {
      const float* xs = x + (size_t)(bm + srow) * 512 + k0 + scol;
      float4 a = *(const float4*)xs, b = *(const float4*)(xs + 4);
      uint4 av; av.x = pkbf2(a.x, a.y); av.y = pkbf2(a.z, a.w);
      av.z = pkbf2(b.x, b.y); av.w = pkbf2(b.z, b.w);
      *(uint4*)(&As[srow][scol]) = av;
      const float* wsrc = Ws + (size_t)(bn + srow) * 1024 + k0 + scol;   // input half k<512
      float4 c = *(const float4*)wsrc, d = *(const float4*)(wsrc + 4);
      uint4 bv; bv.x = pkbf2(c.x, c.y); bv.y = pkbf2(c.z, c.w);
      bv.z = pkbf2(d.x, d.y); bv.w = pkbf2(d.z, d.w);
      *(uint4*)(&Bs[srow][scol]) = bv;
    }
    __syncthreads();
#pragma unroll
    for (int mi = 0; mi < 2; ++mi) {
      bf16x8 a = *(const bf16x8*)(&As[wm * 32 + mi * 16 + (lane & 15)][(lane >> 4) * 8]);
#pragma unroll
      for (int ni = 0; ni < 2; ++ni) {
        bf16x8 b = *(const bf16x8*)(&Bs[wn * 32 + ni * 16 + (lane & 15)][(lane >> 4) * 8]);
        acc[mi][ni] = __builtin_amdgcn_mfma_f32_16x16x32_bf16(a, b, acc[mi][ni], 0, 0, 0);
      }
    }
  }
  const float* bias = (g == 0) ? br : ((g == 1) ? bz : bh);
#pragma unroll
  for (int mi = 0; mi < 2; ++mi)
#pragma unroll
    for (int ni = 0; ni < 2; ++ni) {
      int col  = bn + wn * 32 + ni * 16 + (lane & 15);
      float bv = bias[col];
#pragma unroll
      for (int r = 0; r < 4; ++r) {
        int row = bm + wm * 32 + mi * 16 + (lane >> 4) * 4 + r;
        int bb = row >> 9, ss = row & 511;
        float v = acc[mi][ni][r] + bv;
        P[((size_t)g * 512 + ss) * (64 * 512) + (size_t)bb * 512 + col] =
            __builtin_bit_cast(u16, (_Float16)v);
      }
    }
}

// ---------- kernel 3: GRU scan — one cluster barrier per step ----------
// 16 blocks x 512 thr. cluster c = blockIdx>>2 owns batches 16c..16c+15;
// block q = blockIdx&3:
//   phase A (row-split): rows [128q,128q+128) of W_r,W_z in VGPRs -> r,z
//   phase B (k-split):  W_h[:, 128q..128q+128) in LDS -> f32 partial htilde for ALL 512 j
//   ONE barrier exchanges {partials f32, z f16}; every block reduces redundantly,
//   keeps full h state in f32 registers, writes f16 h into LDS for next MFMA.
__global__ __launch_bounds__(512, 2) void k_gru_scan(
    const float* __restrict__ h0,
    const u16*  __restrict__ P,       // [3][512 ts][64 b][512 j] f16
    const uint4* __restrict__ WF,     // fragment-packed recurrent W (f16)
    float* __restrict__ PT,           // [2][4c][4q][16 b][512 j] f32 partials
    u16* __restrict__ ZX,             // [2][4c][16 b][512 j] f16 z
    u32* __restrict__ flags,          // [512 ts][4 c]
    float* __restrict__ y,
    float* __restrict__ hlast)
{
  const int q = blockIdx.x & 3;
  const int c = blockIdx.x >> 2;
  const int t = threadIdx.x;
  const int w = t >> 6;          // wave 0..7
  const int l = t & 63;
  const int bq = l & 15;         // batch within cluster
  const int g4 = l >> 4;         // 0..3
  const int bglob = c * 16 + bq;

  __shared__ __align__(16) u16 whlds[32 * 4 * 64 * 8];  // 128 KB  [jt][kk][lane][8]
  __shared__ __align__(16) u16 hbuf[16 * 520];          // f16 h   [b][j], pad 8
  __shared__ __align__(16) u16 rhbuf[16 * 136];         // f16 r*h [b][k_local], pad 8

  // --- load W_r/W_z fragments (own rows) into VGPRs ---
  const int rt = q * 8 + w;
  f16x8 wr[16], wz[16];
#pragma unroll
  for (int kt = 0; kt < 16; ++kt) {
    wr[kt] = __builtin_bit_cast(f16x8, WF[((size_t)(0 * 32 + rt) * 16 + kt) * 64 + l]);
    wz[kt] = __builtin_bit_cast(f16x8, WF[((size_t)(1 * 32 + rt) * 16 + kt) * 64 + l]);
  }
  // --- load W_h column-slice fragments into LDS: [jt 0..31][kk 0..3] = WF[2][jt][q*4+kk] ---
#pragma unroll
  for (int it = 0; it < 16; ++it) {
    int i = it * 512 + t;                  // 0..8191
    int jt = i >> 8, kk = (i >> 6) & 3, ln = i & 63;
    uint4 v = WF[((size_t)(2 * 32 + jt) * 16 + (q * 4 + kk)) * 64 + ln];
    *(uint4*)&whlds[((jt * 4 + kk) * 64 + ln) * 8] = v;
  }

  // --- init h: full-state f32 registers (combine mapping) + f16 hbuf ---
  // combine mapping: j = w*64 + jt*16 + g4*4 + r, b = bq
  f32x4 hold[4];
#pragma unroll
  for (int jt = 0; jt < 4; ++jt) {
    int j = w * 64 + jt * 16 + g4 * 4;
    hold[jt] = *(const f32x4*)(h0 + (size_t)bglob * 512 + j);
    uint2 hp; hp.x = pk2h(hold[jt][0], hold[jt][1]); hp.y = pk2h(hold[jt][2], hold[jt][3]);
    *(uint2*)&hbuf[bq * 520 + j] = hp;
  }
  __syncthreads();

  // phase-A row index (own rows)
  const int j0A = q * 128 + w * 16 + g4 * 4;
  const int klA = w * 16 + g4 * 4;             // k_local for rh
  const u16* Ppr = P + (size_t)bglob * 512 + j0A;
  const u16* Ppz = P + PJ_GATE + (size_t)bglob * 512 + j0A;

  // exchange bases (parity-strided)
  const int PT_PAR = 4 * 4 * 16 * 512;         // floats per parity
  const int ZX_PAR = 4 * 16 * 512;             // u16 per parity

  uint2 pru = *(const uint2*)Ppr;
  uint2 pzu = *(const uint2*)Ppz;

  for (int ts = 0; ts < S_; ++ts) {
    const int par = ts & 1;
    // ---- phase A: r,z = sigmoid(W_rz · h + P_rz) for own 128 rows ----
    f32x4 ar = {0.f, 0.f, 0.f, 0.f}, az = {0.f, 0.f, 0.f, 0.f};
#pragma unroll
    for (int kt = 0; kt < 16; ++kt) {
      f16x8 hv = *(const f16x8*)&hbuf[bq * 520 + g4 * 8 + kt * 32];
      ar = __builtin_amdgcn_mfma_f32_16x16x32_f16(wr[kt], hv, ar, 0, 0, 0);
      az = __builtin_amdgcn_mfma_f32_16x16x32_f16(wz[kt], hv, az, 0, 0, 0);
    }
    {
      h2_t pr0 = __builtin_bit_cast(h2_t, pru.x), pr1 = __builtin_bit_cast(h2_t, pru.y);
      h2_t pz0 = __builtin_bit_cast(h2_t, pzu.x), pz1 = __builtin_bit_cast(h2_t, pzu.y);
      float rr0 = sigmoidf_(ar[0] + (float)pr0[0]);
      float rr1 = sigmoidf_(ar[1] + (float)pr0[1]);
      float rr2 = sigmoidf_(ar[2] + (float)pr1[0]);
      float rr3 = sigmoidf_(ar[3] + (float)pr1[1]);
      float zz0 = sigmoidf_(az[0] + (float)pz0[0]);
      float zz1 = sigmoidf_(az[1] + (float)pz0[1]);
      float zz2 = sigmoidf_(az[2] + (float)pz1[0]);
      float zz3 = sigmoidf_(az[3] + (float)pz1[1]);
      // rh = r * h_old (h from f16 hbuf; product is f16 anyway)
      uint2 hAp = *(const uint2*)&hbuf[bq * 520 + j0A];
      h2_t hA0 = __builtin_bit_cast(h2_t, hAp.x), hA1 = __builtin_bit_cast(h2_t, hAp.y);
      uint2 rp;
      rp.x = pk2h(rr0 * (float)hA0[0], rr1 * (float)hA0[1]);
      rp.y = pk2h(rr2 * (float)hA1[0], rr3 * (float)hA1[1]);
      *(uint2*)&rhbuf[bq * 136 + klA] = rp;
      // z -> exchange (f16, [b][j] so combine reads are b64)
      uint2 zp; zp.x = pk2h(zz0, zz1); zp.y = pk2h(zz2, zz3);
      *(uint2*)(ZX + par * ZX_PAR + c * (16 * 512) + bq * 512 + j0A) = zp;
    }
    __syncthreads();   // rhbuf ready

    // ---- phase B: partial htilde (k-split) for ALL 512 j ----
    f32x4 pb0 = {0.f,0.f,0.f,0.f}, pb1 = pb0, pb2 = pb0, pb3 = pb0;
#pragma unroll
    for (int kk = 0; kk < 4; ++kk) {
      f16x8 rv = *(const f16x8*)&rhbuf[bq * 136 + g4 * 8 + kk * 32];
      f16x8 w0 = *(const f16x8*)&whlds[(((w * 4 + 0) * 4 + kk) * 64 + l) * 8];
      f16x8 w1 = *(const f16x8*)&whlds[(((w * 4 + 1) * 4 + kk) * 64 + l) * 8];
      f16x8 w2 = *(const f16x8*)&whlds[(((w * 4 + 2) * 4 + kk) * 64 + l) * 8];
      f16x8 w3 = *(const f16x8*)&whlds[(((w * 4 + 3) * 4 + kk) * 64 + l) * 8];
      pb0 = __builtin_amdgcn_mfma_f32_16x16x32_f16(w0, rv, pb0, 0, 0, 0);
      pb1 = __builtin_amdgcn_mfma_f32_16x16x32_f16(w1, rv, pb1, 0, 0, 0);
      pb2 = __builtin_amdgcn_mfma_f32_16x16x32_f16(w2, rv, pb2, 0, 0, 0);
      pb3 = __builtin_amdgcn_mfma_f32_16x16x32_f16(w3, rv, pb3, 0, 0, 0);
    }
    // store own partials (other 3 blocks' slices of j); keep own in regs
    float* PTme = PT + par * PT_PAR + ((c * 4 + q) * 16 + bq) * 512;
    {
      int jb = w * 64 + g4 * 4;
      *(f32x4*)(PTme + jb)      = pb0;
      *(f32x4*)(PTme + jb + 16) = pb1;
      *(f32x4*)(PTme + jb + 32) = pb2;
      *(f32x4*)(PTme + jb + 48) = pb3;
    }
    // prefetch P_h for combine (independent of exchange)
    uint2 phv[4];
#pragma unroll
    for (int jt = 0; jt < 4; ++jt) {
      int j = w * 64 + jt * 16 + g4 * 4;
      phv[jt] = *(const uint2*)(P + 2 * PJ_GATE + ((size_t)ts * 64 + bglob) * 512 + j);
    }

    __syncthreads();   // all stores issued & drained (vmcnt 0)
    // ---- single cluster barrier ----
    u32* flg = &flags[ts * 4 + c];
    if (t == 0)
      __hip_atomic_fetch_add(flg, 1u, __ATOMIC_RELEASE, __HIP_MEMORY_SCOPE_AGENT);
    while (__hip_atomic_load(flg, __ATOMIC_RELAXED, __HIP_MEMORY_SCOPE_AGENT) < 4u)
      __builtin_amdgcn_s_sleep(1);
    (void)__hip_atomic_load(flg, __ATOMIC_ACQUIRE, __HIP_MEMORY_SCOPE_AGENT);

    // prefetch next step's P_r/P_z
    {
      int tsn = (ts < S_ - 1) ? ts + 1 : ts;
      pru = *(const uint2*)(Ppr + (size_t)tsn * 32768);
      pzu = *(const uint2*)(Ppz + (size_t)tsn * 32768);
    }

    // ---- combine: reduce partials, tanh, gate, update full h ----
    const float* PTc = PT + par * PT_PAR + (c * 4) * (16 * 512);
    const u16*   ZXc = ZX + par * ZX_PAR + c * (16 * 512);
    const bool own = ((w >> 1) == q);
    f32x4 pbl[4] = {pb0, pb1, pb2, pb3};
#pragma unroll
    for (int jt = 0; jt < 4; ++jt) {
      int j = w * 64 + jt * 16 + g4 * 4;
      f32x4 s = pbl[jt];
#pragma unroll
      for (int p = 0; p < 4; ++p) {
        if (p == q) continue;
        s += *(const f32x4*)(PTc + (p * 16 + bq) * 512 + j);
      }
      uint2 zv = *(const uint2*)(ZXc + bq * 512 + j);
      h2_t z0 = __builtin_bit_cast(h2_t, zv.x), z1 = __builtin_bit_cast(h2_t, zv.y);
      h2_t p0 = __builtin_bit_cast(h2_t, phv[jt].x), p1 = __builtin_bit_cast(h2_t, phv[jt].y);
      float ht0 = tanhf_(s[0] + (float)p0[0]);
      float ht1 = tanhf_(s[1] + (float)p0[1]);
      float ht2 = tanhf_(s[2] + (float)p1[0]);
      float ht3 = tanhf_(s[3] + (float)p1[1]);
      float zf0 = (float)z0[0], zf1 = (float)z0[1], zf2 = (float)z1[0], zf3 = (float)z1[1];
      f32x4 hn;
      hn[0] = zf0 * ht0 + (1.f - zf0) * hold[jt][0];
      hn[1] = zf1 * ht1 + (1.f - zf1) * hold[jt][1];
      hn[2] = zf2 * ht2 + (1.f - zf2) * hold[jt][2];
      hn[3] = zf3 * ht3 + (1.f - zf3) * hold[jt][3];
      hold[jt] = hn;
      uint2 hp; hp.x = pk2h(hn[0], hn[1]); hp.y = pk2h(hn[2], hn[3]);
      *(uint2*)&hbuf[bq * 520 + j] = hp;
      if (own)
        __builtin_nontemporal_store(hn,
            (f32x4*)(y + (size_t)bglob * 262144 + (size_t)ts * 512 + j));
    }
    __syncthreads();   // hbuf ready for next phase A
  }

  if ((w >> 1) == q) {
#pragma unroll
    for (int jt = 0; jt < 4; ++jt) {
      int j = w * 64 + jt * 16 + g4 * 4;
      *(f32x4*)(hlast + (size_t)bglob * 512 + j) = hold[jt];
    }
  }
}

// ---------- host ----------
extern "C" void kernel_launch(void* const* d_in, const int* in_sizes, int n_in,
                              void* d_out, int out_size, void* d_ws, size_t ws_size,
                              hipStream_t stream) {
  const float* x  = (const float*)d_in[0];
  const float* h0 = (const float*)d_in[1];
  const float* Wr = (const float*)d_in[2];
  const float* br = (const float*)d_in[3];
  const float* Wz = (const float*)d_in[4];
  const float* bz = (const float*)d_in[5];
  const float* Wh = (const float*)d_in[6];
  const float* bh = (const float*)d_in[7];

  char* ws = (char*)d_ws;
  // layout: WF 1.5MB @0 | P 96MB @2MB | PT 1MB | ZX 128KB | flags 8KB
  uint4* WF    = (uint4*)ws;
  u16*   P     = (u16*)(ws + 2097152);
  float* PT    = (float*)(ws + 102760448);
  u16*   ZX    = (u16*)(ws + 103809024);
  u32*   flags = (u32*)(ws + 103940096);

  float* y     = (float*)d_out;
  float* hlast = y + (size_t)B_ * S_ * H_;

  hipMemsetAsync(flags, 0, 512 * 4 * sizeof(u32), stream);
  k_convert_w<<<dim3(128, 3), dim3(256), 0, stream>>>(Wr, Wz, Wh, WF);
  k_proj_gemm<<<dim3(512, 8, 3), dim3(256), 0, stream>>>(x, Wr, Wz, Wh, br, bz, bh, P);
  k_gru_scan<<<dim3(16), dim3(512), 0, stream>>>(h0, P, WF, PT, ZX, flags, y, hlast);
}

// Round 5
// 3188.134 us; speedup vs baseline: 1.8131x; 1.8131x over previous
//
#include <hip/hip_runtime.h>

#define B_ 64
#define S_ 512
#define H_ 512

typedef unsigned short u16;
typedef unsigned int   u32;
typedef unsigned long long u64;

typedef __attribute__((ext_vector_type(8))) short    bf16x8;
typedef __attribute__((ext_vector_type(8))) _Float16 f16x8;
typedef __attribute__((ext_vector_type(4))) float    f32x4;
typedef __attribute__((ext_vector_type(2))) _Float16 h2_t;

#define PJ_GATE ((size_t)512 * 64 * 512)   // P stride per gate: [512 ts][64 b][512 j]

// ---------- helpers ----------
__device__ inline u16 f2bf(float f) {            // RNE fp32 -> bf16 bits
  u32 u = __builtin_bit_cast(u32, f);
  u32 r = (u + 0x7fffu + ((u >> 16) & 1u)) >> 16;
  return (u16)r;
}
__device__ inline u32 pkbf2(float a, float b) {
  return (u32)f2bf(a) | ((u32)f2bf(b) << 16);
}
__device__ inline u16 f2h(float a) {
  _Float16 x = (_Float16)a;
  return __builtin_bit_cast(u16, x);
}
__device__ inline u32 pk2h(float a, float b) {   // pack two f32 -> half2 bits
  return (u32)f2h(a) | ((u32)f2h(b) << 16);
}
__device__ inline float sigmoidf_(float x) { return 1.f / (1.f + __expf(-x)); }
__device__ inline float tanhf_(float x) {
  float e = __expf(-2.f * fabsf(x));
  float t = (1.f - e) / (1.f + e);
  return copysignf(t, x);
}
__device__ inline void xstore(u32* p, u32 v) {
  __hip_atomic_store(p, v, __ATOMIC_RELAXED, __HIP_MEMORY_SCOPE_AGENT);
}
__device__ inline u64 xload(const u64* p) {
  return __hip_atomic_load(p, __ATOMIC_RELAXED, __HIP_MEMORY_SCOPE_AGENT);
}

// ---------- kernel 1: W recurrent half -> f16 MFMA A-fragments ----------
// WF[g][rt][kt][lane] (uint4) : 8 f16 = W_g[rt*16 + (lane&15)][512 + kt*32 + (lane>>4)*8 + 0..7]
__global__ void k_convert_w(const float* __restrict__ Wr, const float* __restrict__ Wz,
                            const float* __restrict__ Wh, uint4* __restrict__ WF) {
  int g = blockIdx.y;
  const float* Ws = (g == 0) ? Wr : ((g == 1) ? Wz : Wh);
  int i = blockIdx.x * 256 + threadIdx.x;   // 0..32767
  int lane = i & 63;
  int kt   = (i >> 6) & 15;
  int rt   = i >> 10;                       // 0..31
  int row  = rt * 16 + (lane & 15);
  int col  = 512 + kt * 32 + (lane >> 4) * 8;
  const float* src = Ws + (size_t)row * 1024 + col;
  float4 a = *(const float4*)src;
  float4 b = *(const float4*)(src + 4);
  uint4 o;
  o.x = pk2h(a.x, a.y); o.y = pk2h(a.z, a.w);
  o.z = pk2h(b.x, b.y); o.w = pk2h(b.z, b.w);
  WF[((size_t)(g * 32 + rt) * 16 + kt) * 64 + lane] = o;
}

// ---------- kernel 2: projection GEMM (f32 in, bf16 MFMA, f16 out) ----------
// P[g][s][b][j] = f16( sum_k x[b,s,k]*W_g[j,k] + bias_g[j] )
__global__ __launch_bounds__(256) void k_proj_gemm(
    const float* __restrict__ x,      // [B*S][512] f32 (rows m = b*512+s)
    const float* __restrict__ Wr, const float* __restrict__ Wz, const float* __restrict__ Wh,
    const float* __restrict__ br, const float* __restrict__ bz, const float* __restrict__ bh,
    u16* __restrict__ P)
{
  const int g  = blockIdx.z;
  const int bm = blockIdx.x * 64;
  const int bn = blockIdx.y * 64;
  const float* Ws = (g == 0) ? Wr : ((g == 1) ? Wz : Wh);
  __shared__ __align__(16) u16 As[64][32];
  __shared__ __align__(16) u16 Bs[64][32];
  const int tid  = threadIdx.x;
  const int lane = tid & 63;
  const int wm   = (tid >> 6) >> 1;
  const int wn   = (tid >> 6) & 1;
  const int srow = tid >> 2;
  const int scol = (tid & 3) * 8;

  f32x4 zero4 = {0.f, 0.f, 0.f, 0.f};
  f32x4 acc[2][2];
  acc[0][0] = zero4; acc[0][1] = zero4; acc[1][0] = zero4; acc[1][1] = zero4;

  for (int k0 = 0; k0 < 512; k0 += 32) {
    __syncthreads();
    {
      const float* xs = x + (size_t)(bm + srow) * 512 + k0 + scol;
      float4 a = *(const float4*)xs, b = *(const float4*)(xs + 4);
      uint4 av; av.x = pkbf2(a.x, a.y); av.y = pkbf2(a.z, a.w);
      av.z = pkbf2(b.x, b.y); av.w = pkbf2(b.z, b.w);
      *(uint4*)(&As[srow][scol]) = av;
      const float* wsrc = Ws + (size_t)(bn + srow) * 1024 + k0 + scol;   // input half k<512
      float4 c = *(const float4*)wsrc, d = *(const float4*)(wsrc + 4);
      uint4 bv; bv.x = pkbf2(c.x, c.y); bv.y = pkbf2(c.z, c.w);
      bv.z = pkbf2(d.x, d.y); bv.w = pkbf2(d.z, d.w);
      *(uint4*)(&Bs[srow][scol]) = bv;
    }
    __syncthreads();
#pragma unroll
    for (int mi = 0; mi < 2; ++mi) {
      bf16x8 a = *(const bf16x8*)(&As[wm * 32 + mi * 16 + (lane & 15)][(lane >> 4) * 8]);
#pragma unroll
      for (int ni = 0; ni < 2; ++ni) {
        bf16x8 b = *(const bf16x8*)(&Bs[wn * 32 + ni * 16 + (lane & 15)][(lane >> 4) * 8]);
        acc[mi][ni] = __builtin_amdgcn_mfma_f32_16x16x32_bf16(a, b, acc[mi][ni], 0, 0, 0);
      }
    }
  }
  const float* bias = (g == 0) ? br : ((g == 1) ? bz : bh);
#pragma unroll
  for (int mi = 0; mi < 2; ++mi)
#pragma unroll
    for (int ni = 0; ni < 2; ++ni) {
      int col  = bn + wn * 32 + ni * 16 + (lane & 15);
      float bv = bias[col];
#pragma unroll
      for (int r = 0; r < 4; ++r) {
        int row = bm + wm * 32 + mi * 16 + (lane >> 4) * 4 + r;
        int bb = row >> 9, ss = row & 511;
        float v = acc[mi][ni][r] + bv;
        P[((size_t)g * 512 + ss) * (64 * 512) + (size_t)bb * 512 + col] =
            __builtin_bit_cast(u16, (_Float16)v);
      }
    }
}

// ---------- kernel 3: GRU scan — row-split, tag-published fence-free exchange ----------
// 16 blocks x 512 thr. cluster c = blockIdx>>2 owns batches 16c..16c+15;
// block q = blockIdx&3 owns rows [128q,128q+128) of all 3 gates; all W in VGPRs.
// Exchange: u32 slots = (tag<<16)|f16, relaxed agent atomics; readers poll tags.
__global__ __launch_bounds__(512, 2) void k_gru_scan(
    const float* __restrict__ h0,
    const u16*  __restrict__ P,       // [3][512 ts][64 b][512 j] f16
    const uint4* __restrict__ WF,     // fragment-packed recurrent W (f16)
    u32* __restrict__ RHX,            // [2 par][4 c][512 k][16 b] tagged r*h
    u32* __restrict__ HX,             // [2 par][4 c][512 j][16 b] tagged h
    float* __restrict__ y,
    float* __restrict__ hlast)
{
  const int q = blockIdx.x & 3;
  const int c = blockIdx.x >> 2;
  const int t = threadIdx.x;
  const int w = t >> 6;          // wave 0..7
  const int l = t & 63;
  const int bq = l & 15;         // batch within cluster
  const int g4 = l >> 4;         // 0..3
  const int bglob = c * 16 + bq;
  const int rt  = q * 8 + w;
  const int j0A = q * 128 + w * 16 + g4 * 4;   // own rows (4)

  __shared__ __align__(16) u16 hbuf[16 * 520];   // f16 h   [b][j]
  __shared__ __align__(16) u16 rhbuf[16 * 520];  // f16 r*h [b][k]

  // --- all recurrent W fragments in VGPRs (48 x f16x8 = 192 regs) ---
  f16x8 wr[16], wz[16], wh[16];
#pragma unroll
  for (int kt = 0; kt < 16; ++kt) {
    wr[kt] = __builtin_bit_cast(f16x8, WF[((size_t)(0 * 32 + rt) * 16 + kt) * 64 + l]);
    wz[kt] = __builtin_bit_cast(f16x8, WF[((size_t)(1 * 32 + rt) * 16 + kt) * 64 + l]);
    wh[kt] = __builtin_bit_cast(f16x8, WF[((size_t)(2 * 32 + rt) * 16 + kt) * 64 + l]);
  }

  // --- init h ---
  f32x4 hold = *(const f32x4*)(h0 + (size_t)bglob * 512 + j0A);
  {
    int b = t >> 5, j = (t & 31) * 16;
    const float4* s = (const float4*)(h0 + (size_t)(c * 16 + b) * 512 + j);
    float4 v0 = s[0], v1 = s[1], v2 = s[2], v3 = s[3];
    uint4 o0, o1;
    o0.x = pk2h(v0.x, v0.y); o0.y = pk2h(v0.z, v0.w);
    o0.z = pk2h(v1.x, v1.y); o0.w = pk2h(v1.z, v1.w);
    o1.x = pk2h(v2.x, v2.y); o1.y = pk2h(v2.z, v2.w);
    o1.z = pk2h(v3.x, v3.y); o1.w = pk2h(v3.z, v3.w);
    uint4* d = (uint4*)&hbuf[b * 520 + j];
    d[0] = o0; d[1] = o1;
  }
  __syncthreads();

  const u16* Ppr = P + (size_t)bglob * 512 + j0A;
  const u16* Ppz = P + PJ_GATE + (size_t)bglob * 512 + j0A;
  const u16* Pph = P + 2 * PJ_GATE + (size_t)bglob * 512 + j0A;

  // poll-copy mapping: thread t covers k_local = t>>2 (0..127), batches b0..b0+3
  const int kL = t >> 2;
  const int b0 = (t & 3) * 4;
  const int CL = 512 * 16;                 // u32 per cluster
  const int PAR = 4 * CL;                  // u32 per parity

  uint2 pru = *(const uint2*)Ppr;
  uint2 pzu = *(const uint2*)Ppz;

  for (int ts = 0; ts < S_; ++ts) {
    const int par = ts & 1;
    const u32 tag = (u32)(ts + 1);
    const u64 tp  = ((u64)tag << 16) | ((u64)tag << 48);
    u32* RHXp = RHX + par * PAR + c * CL;
    u32* HXp  = HX  + par * PAR + c * CL;

    // prefetch P_h for this step (used in phase B)
    uint2 phu = *(const uint2*)(Pph + (size_t)ts * 32768);

    // ---- phase A: r,z = sigmoid(W_rz · h + P_rz), own 128 rows ----
    f32x4 ar = {0.f, 0.f, 0.f, 0.f}, az = {0.f, 0.f, 0.f, 0.f};
#pragma unroll
    for (int kt = 0; kt < 16; ++kt) {
      f16x8 hv = *(const f16x8*)&hbuf[bq * 520 + g4 * 8 + kt * 32];
      ar = __builtin_amdgcn_mfma_f32_16x16x32_f16(wr[kt], hv, ar, 0, 0, 0);
      az = __builtin_amdgcn_mfma_f32_16x16x32_f16(wz[kt], hv, az, 0, 0, 0);
    }
    h2_t pr0 = __builtin_bit_cast(h2_t, pru.x), pr1 = __builtin_bit_cast(h2_t, pru.y);
    h2_t pz0 = __builtin_bit_cast(h2_t, pzu.x), pz1 = __builtin_bit_cast(h2_t, pzu.y);
    float rr0 = sigmoidf_(ar[0] + (float)pr0[0]);
    float rr1 = sigmoidf_(ar[1] + (float)pr0[1]);
    float rr2 = sigmoidf_(ar[2] + (float)pr1[0]);
    float rr3 = sigmoidf_(ar[3] + (float)pr1[1]);
    float zz0 = sigmoidf_(az[0] + (float)pz0[0]);
    float zz1 = sigmoidf_(az[1] + (float)pz0[1]);
    float zz2 = sigmoidf_(az[2] + (float)pz1[0]);
    float zz3 = sigmoidf_(az[3] + (float)pz1[1]);
    u16 rh0 = f2h(rr0 * hold[0]), rh1 = f2h(rr1 * hold[1]);
    u16 rh2 = f2h(rr2 * hold[2]), rh3 = f2h(rr3 * hold[3]);
    // own rh into LDS + publish tagged slots
    *(uint2*)&rhbuf[bq * 520 + j0A] =
        uint2{(u32)rh0 | ((u32)rh1 << 16), (u32)rh2 | ((u32)rh3 << 16)};
    xstore(RHXp + (j0A + 0) * 16 + bq, (tag << 16) | rh0);
    xstore(RHXp + (j0A + 1) * 16 + bq, (tag << 16) | rh1);
    xstore(RHXp + (j0A + 2) * 16 + bq, (tag << 16) | rh2);
    xstore(RHXp + (j0A + 3) * 16 + bq, (tag << 16) | rh3);

    // ---- poll remote rh quarters -> rhbuf ----
#pragma unroll
    for (int p = 1; p < 4; ++p) {
      int pq = (q + p) & 3;
      int kg = pq * 128 + kL;
      const u64* pa = (const u64*)(RHXp + kg * 16 + b0);
      u64 A = xload(pa), Bv = xload(pa + 1);
      while (((A ^ tp) & 0xffff0000ffff0000ull) != 0ull) {
        __builtin_amdgcn_s_sleep(1);
        A = xload(pa);
      }
      while (((Bv ^ tp) & 0xffff0000ffff0000ull) != 0ull) {
        __builtin_amdgcn_s_sleep(1);
        Bv = xload(pa + 1);
      }
      rhbuf[(b0 + 0) * 520 + kg] = (u16)A;
      rhbuf[(b0 + 1) * 520 + kg] = (u16)(A >> 32);
      rhbuf[(b0 + 2) * 520 + kg] = (u16)Bv;
      rhbuf[(b0 + 3) * 520 + kg] = (u16)(Bv >> 32);
    }
    __syncthreads();

    // ---- phase B: htilde own rows; update h ----
    f32x4 ah = {0.f, 0.f, 0.f, 0.f};
#pragma unroll
    for (int kt = 0; kt < 16; ++kt) {
      f16x8 rv = *(const f16x8*)&rhbuf[bq * 520 + g4 * 8 + kt * 32];
      ah = __builtin_amdgcn_mfma_f32_16x16x32_f16(wh[kt], rv, ah, 0, 0, 0);
    }
    h2_t ph0 = __builtin_bit_cast(h2_t, phu.x), ph1 = __builtin_bit_cast(h2_t, phu.y);
    float ht0 = tanhf_(ah[0] + (float)ph0[0]);
    float ht1 = tanhf_(ah[1] + (float)ph0[1]);
    float ht2 = tanhf_(ah[2] + (float)ph1[0]);
    float ht3 = tanhf_(ah[3] + (float)ph1[1]);
    f32x4 hn;
    hn[0] = zz0 * ht0 + (1.f - zz0) * hold[0];
    hn[1] = zz1 * ht1 + (1.f - zz1) * hold[1];
    hn[2] = zz2 * ht2 + (1.f - zz2) * hold[2];
    hn[3] = zz3 * ht3 + (1.f - zz3) * hold[3];
    hold = hn;
    __builtin_nontemporal_store(hn,
        (f32x4*)(y + (size_t)bglob * 262144 + (size_t)ts * 512 + j0A));
    u16 h0b = f2h(hn[0]), h1b = f2h(hn[1]), h2b = f2h(hn[2]), h3b = f2h(hn[3]);
    *(uint2*)&hbuf[bq * 520 + j0A] =
        uint2{(u32)h0b | ((u32)h1b << 16), (u32)h2b | ((u32)h3b << 16)};
    xstore(HXp + (j0A + 0) * 16 + bq, (tag << 16) | h0b);
    xstore(HXp + (j0A + 1) * 16 + bq, (tag << 16) | h1b);
    xstore(HXp + (j0A + 2) * 16 + bq, (tag << 16) | h2b);
    xstore(HXp + (j0A + 3) * 16 + bq, (tag << 16) | h3b);

    // prefetch next step's P_r/P_z
    {
      int tsn = (ts < S_ - 1) ? ts + 1 : ts;
      pru = *(const uint2*)(Ppr + (size_t)tsn * 32768);
      pzu = *(const uint2*)(Ppz + (size_t)tsn * 32768);
    }

    // ---- poll remote h quarters -> hbuf ----
#pragma unroll
    for (int p = 1; p < 4; ++p) {
      int pq = (q + p) & 3;
      int jg = pq * 128 + kL;
      const u64* pa = (const u64*)(HXp + jg * 16 + b0);
      u64 A = xload(pa), Bv = xload(pa + 1);
      while (((A ^ tp) & 0xffff0000ffff0000ull) != 0ull) {
        __builtin_amdgcn_s_sleep(1);
        A = xload(pa);
      }
      while (((Bv ^ tp) & 0xffff0000ffff0000ull) != 0ull) {
        __builtin_amdgcn_s_sleep(1);
        Bv = xload(pa + 1);
      }
      hbuf[(b0 + 0) * 520 + jg] = (u16)A;
      hbuf[(b0 + 1) * 520 + jg] = (u16)(A >> 32);
      hbuf[(b0 + 2) * 520 + jg] = (u16)Bv;
      hbuf[(b0 + 3) * 520 + jg] = (u16)(Bv >> 32);
    }
    __syncthreads();
  }

  *(f32x4*)(hlast + (size_t)bglob * 512 + j0A) = hold;
}

// ---------- host ----------
extern "C" void kernel_launch(void* const* d_in, const int* in_sizes, int n_in,
                              void* d_out, int out_size, void* d_ws, size_t ws_size,
                              hipStream_t stream) {
  const float* x  = (const float*)d_in[0];
  const float* h0 = (const float*)d_in[1];
  const float* Wr = (const float*)d_in[2];
  const float* br = (const float*)d_in[3];
  const float* Wz = (const float*)d_in[4];
  const float* bz = (const float*)d_in[5];
  const float* Wh = (const float*)d_in[6];
  const float* bh = (const float*)d_in[7];

  char* ws = (char*)d_ws;
  // layout: WF 1.5MB @0 | P 96MB @2MB | RHX 256KB | HX 256KB
  uint4* WF  = (uint4*)ws;
  u16*   P   = (u16*)(ws + 2097152);
  u32*   RHX = (u32*)(ws + 102760448);
  u32*   HX  = (u32*)(ws + 103022592);

  float* y     = (float*)d_out;
  float* hlast = y + (size_t)B_ * S_ * H_;

  hipMemsetAsync(ws + 102760448, 0, 524288, stream);   // clear exchange tags
  k_convert_w<<<dim3(128, 3), dim3(256), 0, stream>>>(Wr, Wz, Wh, WF);
  k_proj_gemm<<<dim3(512, 8, 3), dim3(256), 0, stream>>>(x, Wr, Wz, Wh, br, bz, bh, P);
  k_gru_scan<<<dim3(16), dim3(512), 0, stream>>>(h0, P, WF, RHX, HX, y, hlast);
}